// Round 5
// baseline (212.875 us; speedup 1.0000x reference)
//
#include <hip/hip_runtime.h>

// Y = (Bm@A) @ a_term + (Bm@C) @ c_term as one bf16 MFMA GEMM.
// R5: global_load_lds staging (no VGPR round trip), LDS overlay (Z inside the
// consumed J stage region) -> 16 waves/CU, persistent 4-tile loop so afrags
// load once per wave. Wave-private LDS, no __syncthreads.
// Per-wave LDS dwords: [0..1535] J stage (Z overlay [0..815], epilogue D
// overlay [832..1615]), [1536..2303] X stage.

typedef __bf16 bf16x8 __attribute__((ext_vector_type(8)));
typedef float floatx4 __attribute__((ext_vector_type(4)));

#define RSW 68    // Z row stride in dwords (272 B = 17*16B)
#define WLDS 2320 // per-wave LDS dwords (9280 B, 16B-aligned stride)

typedef const __attribute__((address_space(1))) unsigned guint;
typedef __attribute__((address_space(3))) unsigned suint;

static __device__ __forceinline__ void load16(const float* g, float* l) {
    __builtin_amdgcn_global_load_lds((guint*)g, (suint*)l, 16, 0, 0);
}

__global__ __launch_bounds__(256) void prep_kernel(const float* __restrict__ A,
                                                   const float* __restrict__ Bm,
                                                   const float* __restrict__ C,
                                                   __bf16* __restrict__ acat) {
    int tid = blockIdx.x * 256 + threadIdx.x;  // 0..4095
    int f = tid >> 6;
    int e = tid & 63;
    float m = 0.f, m2 = 0.f;
    #pragma unroll 8
    for (int k = 0; k < 64; ++k) {
        float b = Bm[f * 64 + k];
        m  = fmaf(b, A[k * 64 + e], m);
        m2 = fmaf(b, C[k * 64 + e], m2);
    }
    acat[f * 128 + 2 * e]     = (__bf16)m;   // k = 2e   : M[f,e]
    acat[f * 128 + 2 * e + 1] = (__bf16)m2;  // k = 2e+1 : M2[f,e]
}

static __device__ __forceinline__ unsigned pk(float a, float c) {
    unsigned short ua = __builtin_bit_cast(unsigned short, (__bf16)a);
    unsigned short uc = __builtin_bit_cast(unsigned short, (__bf16)c);
    return ((unsigned)uc << 16) | ua;
}

__global__ __launch_bounds__(256, 4) void main_kernel(const float* __restrict__ X,
                                                      const float* __restrict__ J,
                                                      const __bf16* __restrict__ acat,
                                                      float* __restrict__ out) {
    __shared__ __align__(16) float buf[4][WLDS];  // 37,120 B -> 4 blocks/CU

    const int wave = threadIdx.x >> 6;
    const int lane = threadIdx.x & 63;
    const int l15  = lane & 15;
    const int quad = lane >> 4;
    float* stg = buf[wave];

    // ---- A-fragments: once per wave (amortized over 4 tiles = 16 points) ----
    bf16x8 afrag[4][4];
    #pragma unroll
    for (int mt = 0; mt < 4; ++mt)
        #pragma unroll
        for (int kc = 0; kc < 4; ++kc)
            afrag[mt][kc] = *(const bf16x8*)(acat + (mt * 16 + l15) * 128 + kc * 32 + quad * 8);

    #pragma unroll 1
    for (int it = 0; it < 4; ++it) {
        const int tile = it * 4096 + blockIdx.x * 4 + wave;
        const size_t pbase = (size_t)tile * 4;  // 4 points per tile

        // ---- stage J (6 KB) + X (3 KB) via async direct-to-LDS DMA ----
        const float* jg = J + pbase * 384;
        const float* xg = X + pbase * 192;
        #pragma unroll
        for (int t = 0; t < 6; ++t) load16(jg + (t * 64 + lane) * 4, stg + t * 256);
        #pragma unroll
        for (int t = 0; t < 3; ++t) load16(xg + (t * 64 + lane) * 4, stg + 1536 + t * 256);

        __asm__ volatile("s_waitcnt vmcnt(0)" ::: "memory");

        unsigned* zw = (unsigned*)stg;  // Z overlay [0..815]

        // ---- phase 1: geometry, lane = d, records gathered from LDS ----
        // Z writes for point pi end below J records of point pi+1 (safe overlay).
        #pragma unroll
        for (int pi = 0; pi < 4; ++pi) {
            const float* jst = stg + pi * 384 + lane * 6;
            float2 ja = *(const float2*)(jst);
            float2 jb = *(const float2*)(jst + 2);
            float2 jc = *(const float2*)(jst + 4);
            const float* xst = stg + 1536 + pi * 192 + lane * 3;
            float xx = xst[0], xy = xst[1], xz = xst[2];

            float a0x = ja.x, a0y = jb.x, a0z = jc.x;  // J col 0
            float a1x = ja.y, a1y = jb.y, a1z = jc.y;  // J col 1

            float n0 = sqrtf(a0x * a0x + a0y * a0y + a0z * a0z);
            float r0 = 1.0f / fmaxf(n0, 1e-12f);
            float b1x = a0x * r0, b1y = a0y * r0, b1z = a0z * r0;

            float d  = b1x * a1x + b1y * a1y + b1z * a1z;
            float ux = a1x - d * b1x, uy = a1y - d * b1y, uz = a1z - d * b1z;
            float n2 = sqrtf(ux * ux + uy * uy + uz * uz);
            float r2 = 1.0f / fmaxf(n2, 1e-12f);
            float b2x = ux * r2, b2y = uy * r2, b2z = uz * r2;

            float b3x = b1y * b2z - b1z * b2y;
            float b3y = b1z * b2x - b1x * b2z;
            float b3z = b1x * b2y - b1y * b2x;

            float rt0 = b1x * xx + b1y * xy + b1z * xz;
            float rt1 = b2x * xx + b2y * xy + b2z * xz;
            float rt2 = b3x * xx + b3y * xy + b3z * xz;

            float s = rt1 - rt2, t = rt1 + rt2;

            unsigned* zr = zw + (pi * 3) * RSW;
            zr[lane]           = pk(b2x * s + b3x * t, b1x * rt0);
            zr[RSW + lane]     = pk(b2y * s + b3y * t, b1y * rt0);
            zr[2 * RSW + lane] = pk(b2z * s + b3z * t, b1z * rt0);
        }

        __asm__ volatile("s_waitcnt lgkmcnt(0)" ::: "memory");

        // ---- phase 2: 16x mfma 16x16x32, K=128, rows 0..11 valid ----
        floatx4 acc[4];
        #pragma unroll
        for (int mt = 0; mt < 4; ++mt) acc[mt] = (floatx4){0.f, 0.f, 0.f, 0.f};

        int row = l15 > 11 ? 11 : l15;  // n>=12 columns are garbage, never stored
        #pragma unroll
        for (int kc = 0; kc < 4; ++kc) {
            bf16x8 b = *(const bf16x8*)((const __bf16*)zw + row * 136 + kc * 32 + quad * 8);
            #pragma unroll
            for (int mt = 0; mt < 4; ++mt)
                acc[mt] = __builtin_amdgcn_mfma_f32_16x16x32_bf16(afrag[mt][kc], b, acc[mt], 0, 0, 0);
        }

        // ---- epilogue: D[f][n] -> LDS [832 + p_local*196 + f*3 + i] ----
        float* dl = stg + 832;
        #pragma unroll
        for (int mt = 0; mt < 4; ++mt) {
            int n = l15;
            if (n < 12) {
                int pl = (n * 21846) >> 16;  // n / 3
                int i  = n - pl * 3;
                float* dst = dl + pl * 196 + i;
                #pragma unroll
                for (int r = 0; r < 4; ++r) {
                    int f = mt * 16 + quad * 4 + r;
                    dst[f * 3] = acc[mt][r];
                }
            }
        }

        __asm__ volatile("s_waitcnt lgkmcnt(0)" ::: "memory");

        // ---- coalesced store: 4 points x 48 float4 ----
        floatx4* og = (floatx4*)(out + pbase * 192);
        #pragma unroll
        for (int t = 0; t < 3; ++t) {
            int g  = t * 64 + lane;
            int pg = (g * 1366) >> 16;  // g / 48
            int o  = g - pg * 48;
            og[g] = *(const floatx4*)(dl + pg * 196 + o * 4);
        }
    }
}

extern "C" void kernel_launch(void* const* d_in, const int* in_sizes, int n_in,
                              void* d_out, int out_size, void* d_ws, size_t ws_size,
                              hipStream_t stream) {
    const float* X  = (const float*)d_in[0];
    const float* J  = (const float*)d_in[1];
    const float* A  = (const float*)d_in[2];
    const float* Bm = (const float*)d_in[3];
    const float* C  = (const float*)d_in[4];
    float* out = (float*)d_out;
    __bf16* acat = (__bf16*)d_ws;  // 64x128 bf16 = 16 KB

    prep_kernel<<<16, 256, 0, stream>>>(A, Bm, C, acat);

    // 65536 points = 1024 blocks x 4 waves x 4 iterations x 4 points
    main_kernel<<<1024, 256, 0, stream>>>(X, J, acat, out);
}

// Round 6
// 211.337 us; speedup vs baseline: 1.0073x; 1.0073x over previous
//
#include <hip/hip_runtime.h>

// Y = (Bm@A) @ a_term + (Bm@C) @ c_term as one bf16 MFMA GEMM.
// R6: software-pipelined wave-private staging. Double-buffered J stage,
// prefetch of tile i+1 issued during tile i, fine-grained vmcnt(16) at loop
// top (output stores stay in flight). MFMA operands swapped (Z = A-operand,
// Acat = B-operand) -> D[n][f] stores directly from acc: no LDS epilogue,
// only ONE lgkm full-stop per iteration. No __syncthreads anywhere.
// Per-wave LDS dwords: Jbuf0 [0..1535], Jbuf1 [1536..3071], X [3072..3839].
// Z (12 rows x 68 dw = 816 dw) overlays the consumed J buffer.

typedef __bf16 bf16x8 __attribute__((ext_vector_type(8)));
typedef float floatx4 __attribute__((ext_vector_type(4)));

#define RSW 68     // Z row stride in dwords (272 B = 17*16B)
#define ITERS 8    // tiles per wave (4 points each)

typedef const __attribute__((address_space(1))) unsigned guint;
typedef __attribute__((address_space(3))) unsigned suint;

static __device__ __forceinline__ void load16(const float* g, float* l) {
    __builtin_amdgcn_global_load_lds((guint*)g, (suint*)l, 16, 0, 0);
}

__global__ __launch_bounds__(256) void prep_kernel(const float* __restrict__ A,
                                                   const float* __restrict__ Bm,
                                                   const float* __restrict__ C,
                                                   __bf16* __restrict__ acat) {
    int tid = blockIdx.x * 256 + threadIdx.x;  // 0..4095
    int f = tid >> 6;
    int e = tid & 63;
    float m = 0.f, m2 = 0.f;
    #pragma unroll 8
    for (int k = 0; k < 64; ++k) {
        float b = Bm[f * 64 + k];
        m  = fmaf(b, A[k * 64 + e], m);
        m2 = fmaf(b, C[k * 64 + e], m2);
    }
    acat[f * 128 + 2 * e]     = (__bf16)m;   // k = 2e   : M[f,e]
    acat[f * 128 + 2 * e + 1] = (__bf16)m2;  // k = 2e+1 : M2[f,e]
}

static __device__ __forceinline__ unsigned pk(float a, float c) {
    unsigned short ua = __builtin_bit_cast(unsigned short, (__bf16)a);
    unsigned short uc = __builtin_bit_cast(unsigned short, (__bf16)c);
    return ((unsigned)uc << 16) | ua;
}

__global__ __launch_bounds__(256, 2) void main_kernel(const float* __restrict__ X,
                                                      const float* __restrict__ J,
                                                      const __bf16* __restrict__ acat,
                                                      float* __restrict__ out) {
    __shared__ __align__(16) float buf[4][3840];  // 61,440 B -> 2 blocks/CU

    const int wave = threadIdx.x >> 6;
    const int lane = threadIdx.x & 63;
    const int l15  = lane & 15;
    const int quad = lane >> 4;
    float* stg = buf[wave];
    float* xb  = stg + 3072;

    const int wid = blockIdx.x * 4 + wave;  // 0..2047

    // ---- Acat fragments (used as B-operand): once per wave ----
    bf16x8 afrag[4][4];
    #pragma unroll
    for (int ft = 0; ft < 4; ++ft)
        #pragma unroll
        for (int kc = 0; kc < 4; ++kc)
            afrag[ft][kc] = *(const bf16x8*)(acat + (ft * 16 + l15) * 128 + kc * 32 + quad * 8);

    // per-lane store helpers: n = quad*4 + r
    const int f3 = l15 * 3;

    // ---- prologue: stage tile 0 ----
    {
        const size_t pb0 = (size_t)wid * 4;
        const float* jg = J + pb0 * 384;
        const float* xg = X + pb0 * 192;
        #pragma unroll
        for (int t = 0; t < 6; ++t) load16(jg + (t * 64 + lane) * 4, stg + t * 256);
        #pragma unroll
        for (int t = 0; t < 3; ++t) load16(xg + (t * 64 + lane) * 4, xb + t * 256);
    }
    __asm__ volatile("s_waitcnt vmcnt(0)" ::: "memory");

    #pragma unroll 1
    for (int it = 0; it < ITERS; ++it) {
        const int sel = it & 1;
        float* jb = stg + sel * 1536;
        const size_t pbase = ((size_t)it * 2048 + wid) * 4;  // 4 points per tile

        // steady-state wait: drains this tile's prefetch DMAs (issued one
        // iteration ago), leaves the 16 newer output stores in flight.
        __asm__ volatile("s_waitcnt vmcnt(16)" ::: "memory");

        unsigned* zw = (unsigned*)jb;  // Z overlay on consumed J region

        // ---- phase 1: geometry, lane = d ----
        #pragma unroll
        for (int pi = 0; pi < 4; ++pi) {
            const float* jst = jb + pi * 384 + lane * 6;
            float2 ja = *(const float2*)(jst);
            float2 jbv = *(const float2*)(jst + 2);
            float2 jc = *(const float2*)(jst + 4);
            const float* xst = xb + pi * 192 + lane * 3;
            float xx = xst[0], xy = xst[1], xz = xst[2];

            float a0x = ja.x, a0y = jbv.x, a0z = jc.x;  // J col 0
            float a1x = ja.y, a1y = jbv.y, a1z = jc.y;  // J col 1

            float n0 = sqrtf(a0x * a0x + a0y * a0y + a0z * a0z);
            float r0 = 1.0f / fmaxf(n0, 1e-12f);
            float b1x = a0x * r0, b1y = a0y * r0, b1z = a0z * r0;

            float d  = b1x * a1x + b1y * a1y + b1z * a1z;
            float ux = a1x - d * b1x, uy = a1y - d * b1y, uz = a1z - d * b1z;
            float n2 = sqrtf(ux * ux + uy * uy + uz * uz);
            float r2 = 1.0f / fmaxf(n2, 1e-12f);
            float b2x = ux * r2, b2y = uy * r2, b2z = uz * r2;

            float b3x = b1y * b2z - b1z * b2y;
            float b3y = b1z * b2x - b1x * b2z;
            float b3z = b1x * b2y - b1y * b2x;

            float rt0 = b1x * xx + b1y * xy + b1z * xz;
            float rt1 = b2x * xx + b2y * xy + b2z * xz;
            float rt2 = b3x * xx + b3y * xy + b3z * xz;

            float s = rt1 - rt2, t = rt1 + rt2;

            unsigned* zr = zw + (pi * 3) * RSW;
            zr[lane]           = pk(b2x * s + b3x * t, b1x * rt0);
            zr[RSW + lane]     = pk(b2y * s + b3y * t, b1y * rt0);
            zr[2 * RSW + lane] = pk(b2z * s + b3z * t, b1z * rt0);
        }

        // ---- prefetch J for tile it+1 into the other J buffer ----
        if (it + 1 < ITERS) {
            const size_t pbn = ((size_t)(it + 1) * 2048 + wid) * 4;
            const float* jg = J + pbn * 384;
            float* jbn = stg + (sel ^ 1) * 1536;
            #pragma unroll
            for (int t = 0; t < 6; ++t) load16(jg + (t * 64 + lane) * 4, jbn + t * 256);
        }

        // drain DS: Z writes visible, X reads done (X buffer reusable)
        __asm__ volatile("s_waitcnt lgkmcnt(0)" ::: "memory");

        // ---- prefetch X for tile it+1 (single X buffer, reads drained) ----
        if (it + 1 < ITERS) {
            const size_t pbn = ((size_t)(it + 1) * 2048 + wid) * 4;
            const float* xg = X + pbn * 192;
            #pragma unroll
            for (int t = 0; t < 3; ++t) load16(xg + (t * 64 + lane) * 4, xb + t * 256);
        }

        // ---- phase 2: Z as A-operand, Acat as B-operand -> D[n][f] ----
        floatx4 acc[4];
        #pragma unroll
        for (int ft = 0; ft < 4; ++ft) acc[ft] = (floatx4){0.f, 0.f, 0.f, 0.f};

        int row = l15 > 11 ? 11 : l15;  // n>=12 rows are garbage, never stored
        #pragma unroll
        for (int kc = 0; kc < 4; ++kc) {
            bf16x8 zf = *(const bf16x8*)((const __bf16*)zw + row * 136 + kc * 32 + quad * 8);
            #pragma unroll
            for (int ft = 0; ft < 4; ++ft)
                acc[ft] = __builtin_amdgcn_mfma_f32_16x16x32_bf16(zf, afrag[ft][kc], acc[ft], 0, 0, 0);
        }

        // ---- store directly from acc: D[n = quad*4+r][f = ft*16+l15] ----
        // n -> point pl = n/3, component i = n%3; lanes quad==3 have n>=12: skip
        if (quad < 3) {
            float* base = out + pbase * 192 + f3;
            #pragma unroll
            for (int r = 0; r < 4; ++r) {
                int n  = quad * 4 + r;
                int pl = (n * 11) >> 5;  // n/3 for n<16
                int i  = n - pl * 3;
                float* dst = base + pl * 192 + i;
                #pragma unroll
                for (int ft = 0; ft < 4; ++ft)
                    dst[ft * 48] = acc[ft][r];
            }
        }
    }
}

extern "C" void kernel_launch(void* const* d_in, const int* in_sizes, int n_in,
                              void* d_out, int out_size, void* d_ws, size_t ws_size,
                              hipStream_t stream) {
    const float* X  = (const float*)d_in[0];
    const float* J  = (const float*)d_in[1];
    const float* A  = (const float*)d_in[2];
    const float* Bm = (const float*)d_in[3];
    const float* C  = (const float*)d_in[4];
    float* out = (float*)d_out;
    __bf16* acat = (__bf16*)d_ws;  // 64x128 bf16 = 16 KB

    prep_kernel<<<16, 256, 0, stream>>>(A, Bm, C, acat);

    // 65536 points = 512 blocks x 4 waves x 8 iterations x 4 points
    main_kernel<<<512, 256, 0, stream>>>(X, J, acat, out);
}